// Round 13
// baseline (764.873 us; speedup 1.0000x reference)
//
#include <hip/hip_runtime.h>
#include <hip/hip_fp16.h>

#define BB 16
#define NN 1024
#define DD 256
#define NSLAB 16        // sinkhorn slabs per batch (64 rows each)
#define ETW 40          // bary: padded LDS row width (halves)

typedef _Float16 h8 __attribute__((ext_vector_type(8)));
typedef _Float16 hv4 __attribute__((ext_vector_type(4)));
typedef _Float16 h2 __attribute__((ext_vector_type(2)));
typedef float f32x4 __attribute__((ext_vector_type(4)));

#if __has_builtin(__builtin_amdgcn_exp2f)
#define EXP2F(x) __builtin_amdgcn_exp2f(x)
#else
#define EXP2F(x) exp2f(x)
#endif
#if __has_builtin(__builtin_amdgcn_logf)
#define LOG2F(x) __builtin_amdgcn_logf(x)
#else
#define LOG2F(x) log2f(x)
#endif

// log2-domain: A2s = -100*log2e*relu(1-S) - CPOS2*|i-j|   (pos prior folded in, fp16)
constexpr float K_A2  = -144.26950408889634f;                 // -100*log2(e)
constexpr float CPOS2 = (float)(0.2 * 1.4426950408889634 / 1023.0);
constexpr float C1    = 0.06931471805599453f;                 // ln2/10
constexpr float BASE2 = -10.0f;                               // log2(1/1024 + 1e-12)
constexpr float P2B   = 0x1p-10f;                             // 2^BASE2

#define PIDX(i) ((i) + ((i) >> 3))

__device__ __forceinline__ float waveReduceSum(float v) {
#pragma unroll
  for (int o = 32; o; o >>= 1) v += __shfl_xor(v, o);
  return v;
}

__device__ __forceinline__ void ldsVec16p(const float* lds, int j0, float (&out)[16]) {
#pragma unroll
  for (int k = 0; k < 8; ++k) {
    out[k] = lds[PIDX(j0 + k)];
    out[8 + k] = lds[PIDX(512 + j0 + k)];
  }
}

// ---------------- K1: normalize rows of X and Y -> fp16 ----------------
__global__ __launch_bounds__(256) void normalize_kernel(
    const float* __restrict__ X, const float* __restrict__ Y,
    _Float16* __restrict__ Xh, _Float16* __restrict__ Yh) {
  int wave = threadIdx.x >> 6;
  int lane = threadIdx.x & 63;
  int row = blockIdx.x * 4 + wave;
  const float* src;
  _Float16* dst;
  if (row < BB * NN) { src = X + (size_t)row * DD; dst = Xh + (size_t)row * DD; }
  else { int r2 = row - BB * NN; src = Y + (size_t)r2 * DD; dst = Yh + (size_t)r2 * DD; }
  float4 v = *(const float4*)(src + lane * 4);
  float ss = v.x * v.x + v.y * v.y + v.z * v.z + v.w * v.w;
  ss = waveReduceSum(ss);
  float sc = 1.0f / fmaxf(sqrtf(ss), 1e-12f);
  hv4 hv;
  hv[0] = (_Float16)(v.x * sc); hv[1] = (_Float16)(v.y * sc);
  hv[2] = (_Float16)(v.z * sc); hv[3] = (_Float16)(v.w * sc);
  *(hv4*)(dst + lane * 4) = hv;
}

// ---------------- K1b: tiled transpose X,Y -> fp16 [b][d][n] ----------------
__global__ __launch_bounds__(256) void transpose_kernel(
    const float* __restrict__ X, const float* __restrict__ Y,
    _Float16* __restrict__ XT, _Float16* __restrict__ YT) {
  __shared__ _Float16 tile[64][72];
  int zb = blockIdx.z;
  const float* E;
  _Float16* ET;
  if (zb < BB) { E = X + (size_t)zb * NN * DD; ET = XT + (size_t)zb * DD * NN; }
  else { E = Y + (size_t)(zb - BB) * NN * DD; ET = YT + (size_t)(zb - BB) * DD * NN; }
  int n0 = blockIdx.x * 64, d0 = blockIdx.y * 64;
  int t = threadIdx.x;
  int lr = t >> 2, lc = (t & 3) * 16;
#pragma unroll
  for (int k = 0; k < 16; k += 4) {
    float4 v = *(const float4*)(E + (size_t)(n0 + lr) * DD + d0 + lc + k);
    tile[lc + k + 0][lr] = (_Float16)v.x;
    tile[lc + k + 1][lr] = (_Float16)v.y;
    tile[lc + k + 2][lr] = (_Float16)v.z;
    tile[lc + k + 3][lr] = (_Float16)v.w;
  }
  __syncthreads();
#pragma unroll
  for (int k = 0; k < 16; k += 8) {
    h8 o;
#pragma unroll
    for (int j = 0; j < 8; ++j) o[j] = tile[lr][lc + k + j];
    *(h8*)(ET + (size_t)(d0 + lr) * NN + n0 + lc + k) = o;
  }
}

// ---------------- K2: ONE S-gemm per (b, tile), dual-write A2 + A2T ---------
__global__ __launch_bounds__(256) void gemm_a2_kernel(
    const _Float16* __restrict__ Xh, const _Float16* __restrict__ Yh,
    _Float16* __restrict__ A2, _Float16* __restrict__ A2T) {
  __shared__ _Float16 tile[128][136];
  const int b = blockIdx.z;
  const int I0 = blockIdx.y * 128;
  const int J0 = blockIdx.x * 128;
  const int lane = threadIdx.x & 63;
  const int wave = threadIdx.x >> 6;
  const int m = lane & 15, quad = lane >> 4;
  const _Float16* Abase = Xh + ((size_t)b * NN + I0 + wave * 32) * DD;
  const _Float16* Bbase = Yh + ((size_t)b * NN + J0) * DD;
  f32x4 acc[2][8] = {};
  for (int k0 = 0; k0 < DD; k0 += 32) {
    int koff = k0 + quad * 8;
    h8 a0 = *(const h8*)(Abase + (size_t)m * DD + koff);
    h8 a1 = *(const h8*)(Abase + (size_t)(m + 16) * DD + koff);
#pragma unroll
    for (int t = 0; t < 8; ++t) {
      h8 bf = *(const h8*)(Bbase + (size_t)(t * 16 + m) * DD + koff);
      acc[0][t] = __builtin_amdgcn_mfma_f32_16x16x32_f16(a0, bf, acc[0][t], 0, 0, 0);
      acc[1][t] = __builtin_amdgcn_mfma_f32_16x16x32_f16(a1, bf, acc[1][t], 0, 0, 0);
    }
  }
#pragma unroll
  for (int a = 0; a < 2; ++a)
#pragma unroll
    for (int t = 0; t < 8; ++t)
#pragma unroll
      for (int r = 0; r < 4; ++r) {
        int row = wave * 32 + a * 16 + quad * 4 + r;   // 0..127
        int col = t * 16 + m;                          // 0..127
        float s = acc[a][t][r];
        float ri = (float)(I0 + row);
        float ci = (float)(J0 + col);
        tile[row][col] =
            (_Float16)(K_A2 * fmaxf(1.0f - s, 0.0f) - CPOS2 * fabsf(ri - ci));
      }
  __syncthreads();
  const int t = threadIdx.x;
  // A2 write: row rr = t>>1, chunks (t&1)*8 + i (16 x 8 halves = 128 cols)
  {
    int rr = t >> 1;
    _Float16* Orow = A2 + ((size_t)b * NN + I0 + rr) * NN + J0;
#pragma unroll
    for (int i = 0; i < 8; ++i) {
      int cc = ((t & 1) * 8 + i) * 8;
      h8 o;
#pragma unroll
      for (int j = 0; j < 8; ++j) o[j] = tile[rr][cc + j];
      *(h8*)(Orow + cc) = o;
    }
  }
  // A2T write: A2T[J0+cr][I0+cc] = tile[cc][cr]
  {
    int ch = t & 15;                                  // cc chunk: cc = ch*8+j
    int crb = t >> 4;                                 // 0..15
#pragma unroll
    for (int i = 0; i < 8; ++i) {
      int cr = crb + i * 16;                          // 0..127
      h8 o;
#pragma unroll
      for (int j = 0; j < 8; ++j) o[j] = tile[ch * 8 + j][cr];
      *(h8*)(A2T + ((size_t)b * NN + J0 + cr) * NN + I0 + ch * 8) = o;
    }
  }
}

// ---------------- K3: persistent sinkhorn, wave-level barrier arrive --------
// 256 blocks = (16 slabs x 64 rows, 16 batches), 512 threads, 1 block/CU,
// PLAIN launch. New in R13: barrier ARRIVE is per-WAVE, not per-block. Each
// wave drains its own vmcnt(0) after its pass-B atomic adds (the identical
// release mechanism __syncthreads uses, at wave granularity) and lane 0 bumps
// the counter; detect target = 128*(it+1) (8 waves x 16 blocks). Removes one
// __syncthreads per iteration AND lets the global chain start as soon as the
// last WAVE (not block) finishes. Zero-store ordering: each wave's zeroes
// precede its own bump; readers wait 2 full arrival generations later.
#define SINK_SMEM (131072 + 4608 + 256 + 256 + 256 + 256)
#define ARRIVE_PER_IT (NSLAB * 8)

__device__ __forceinline__ void storePart2(float* p, float2 v) {
  union { float2 v; unsigned long long u; } cv;
  cv.v = v;
  __hip_atomic_store((unsigned long long*)p, cv.u, __ATOMIC_RELAXED,
                     __HIP_MEMORY_SCOPE_AGENT);
}

__device__ __forceinline__ float2 loadPart2(const float* p) {
  union { float2 v; unsigned long long u; } cv;
  cv.u = __hip_atomic_load((const unsigned long long*)p, __ATOMIC_RELAXED,
                           __HIP_MEMORY_SCOPE_AGENT);
  return cv.v;
}

__device__ __forceinline__ void atomAddF(float* p, float v) {
  (void)__hip_atomic_fetch_add(p, v, __ATOMIC_RELAXED, __HIP_MEMORY_SCOPE_AGENT);
}

// 16-B cache-bypassing (coherent) load: reads at the L3 coherence point,
// where the agent-scope atomic adds execute.
__device__ __forceinline__ float4 loadCoh4(const float* p) {
  float4 v;
  asm volatile("global_load_dwordx4 %0, %1, off sc0 sc1\n\ts_waitcnt vmcnt(0)"
               : "=v"(v)
               : "v"(p)
               : "memory");
  return v;
}

__global__ __launch_bounds__(512) void sink_persist(
    const _Float16* __restrict__ A2, float* __restrict__ Cbuf,
    float* __restrict__ Fv, float* __restrict__ Gf,
    float* __restrict__ rOut, float* __restrict__ cOut, float* __restrict__ Lrow,
    unsigned* __restrict__ bar) {
  extern __shared__ char smem[];
  _Float16* slab = (_Float16*)smem;                      // [64][1024] fp16 K'
  float* lv = (float*)(smem + 131072);                   // padded w, NN + NN/8
  float* f_l = (float*)(smem + 135680);                  // [64] u_i
  float* m_l = (float*)(smem + 135936);                  // [64] row max of a2
  float* fv_l = (float*)(smem + 136192);                 // [64] final log-f
  volatile unsigned* dflag = (volatile unsigned*)(smem + 136448);
  const int b = blockIdx.y;
  const int slabId = blockIdx.x;                         // 0..15
  const int t = threadIdx.x, lane = t & 63, wave = t >> 6;
  unsigned* barB = bar + b * 16;                         // 64 B padded counters

  // one-time: stage this block's 64-row A2 slab into LDS
  const _Float16* src = A2 + ((size_t)b * NN + slabId * 64) * NN;
  for (int e = t * 8; e < 64 * NN; e += 512 * 8)
    *(h8*)(slab + e) = *(const h8*)(src + e);
  __syncthreads();

  const int j0 = lane * 8;
  const int r0w = wave * 8;                              // 8 rows per wave

  // prologue: per-row max (batched shuffle reduce), then K' = exp2(a2 - m)
  {
    h8 qa8[8], qb8[8];
#pragma unroll
    for (int r = 0; r < 8; ++r) {
      qa8[r] = *(const h8*)(slab + (size_t)(r0w + r) * NN + j0);
      qb8[r] = *(const h8*)(slab + (size_t)(r0w + r) * NN + 512 + j0);
    }
    float mr[8];
#pragma unroll
    for (int r = 0; r < 8; ++r) {
      float m = (float)qa8[r][0];
#pragma unroll
      for (int k = 1; k < 8; ++k) m = fmaxf(m, (float)qa8[r][k]);
#pragma unroll
      for (int k = 0; k < 8; ++k) m = fmaxf(m, (float)qb8[r][k]);
      mr[r] = m;
    }
#pragma unroll
    for (int o = 32; o; o >>= 1)
#pragma unroll
      for (int r = 0; r < 8; ++r) mr[r] = fmaxf(mr[r], __shfl_xor(mr[r], o));
#pragma unroll
    for (int r = 0; r < 8; ++r) {
      h8 oa, ob;
#pragma unroll
      for (int k = 0; k < 8; ++k) {
        oa[k] = (_Float16)EXP2F((float)qa8[r][k] - mr[r]);
        ob[k] = (_Float16)EXP2F((float)qb8[r][k] - mr[r]);
      }
      *(h8*)(slab + (size_t)(r0w + r) * NN + j0) = oa;
      *(h8*)(slab + (size_t)(r0w + r) * NN + 512 + j0) = ob;
      if (lane == 0) m_l[r0w + r] = mr[r];
    }
  }

  const size_t CB = (size_t)BB * NN;
  float gv[16];

  for (int it = 0; it < 50; ++it) {
    // prologue: w from previous iteration's accumulated col sums
    if (it == 0) {
      lv[PIDX(2 * t)] = 1.0f;
      lv[PIDX(2 * t + 1)] = 1.0f;
    } else if (t < 256) {
      const float* Cr = Cbuf + (size_t)((it + 2) % 3) * CB + b * NN;  // (it-1)%3
      float4 cc = loadCoh4(Cr + 4 * t);
      lv[PIDX(4 * t + 0)] = P2B / cc.x;
      lv[PIDX(4 * t + 1)] = P2B / cc.y;
      lv[PIDX(4 * t + 2)] = P2B / cc.z;
      lv[PIDX(4 * t + 3)] = P2B / cc.w;
    }
    if (t == 0) *dflag = 0;
    __syncthreads();
    ldsVec16p(lv, j0, gv);
    // zero my stripe of the (it+1)%3 buffer (read at it+2; adds at it+1 --
    // ordered before this wave's arrive; readers are 2 generations later).
    {
      float* Cz = Cbuf + (size_t)((it + 1) % 3) * CB + b * NN;
      if (t < 32) storePart2(Cz + slabId * 64 + 2 * t, make_float2(0.f, 0.f));
    }
    // pass A: 8 rows per wave, s_i = sum K' * w (pure FMA, batched reduce)
    float sr8[8];
#pragma unroll
    for (int r = 0; r < 8; ++r) {
      h8 qa = *(const h8*)(slab + (size_t)(r0w + r) * NN + j0);
      h8 qb = *(const h8*)(slab + (size_t)(r0w + r) * NN + 512 + j0);
      float s = 0.f;
#pragma unroll
      for (int k = 0; k < 8; ++k) s = fmaf((float)qa[k], gv[k], s);
#pragma unroll
      for (int k = 0; k < 8; ++k) s = fmaf((float)qb[k], gv[8 + k], s);
      sr8[r] = s;
    }
#pragma unroll
    for (int o = 32; o; o >>= 1)
#pragma unroll
      for (int r = 0; r < 8; ++r) sr8[r] += __shfl_xor(sr8[r], o);
    if (lane == 0) {
#pragma unroll
      for (int r = 0; r < 8; ++r) {
        f_l[r0w + r] = P2B / sr8[r];                     // u_i
        if (it == 49) {
          float flog = BASE2 - m_l[r0w + r] - LOG2F(sr8[r]);
          fv_l[r0w + r] = flog;
          Fv[b * NN + slabId * 64 + r0w + r] = flog;
        }
      }
    }
    __syncthreads();
    // pass B: per-thread column pair over 64 LDS rows, then HW-accumulate
    float p0 = 0.f, p1 = 0.f;
    const _Float16* cp = slab + 2 * t;
#pragma unroll 4
    for (int i4 = 0; i4 < 16; ++i4) {
      float4 u4 = *(const float4*)&f_l[i4 * 4];
#pragma unroll
      for (int q = 0; q < 4; ++q) {
        h2 a = *(const h2*)(cp + (size_t)(i4 * 4 + q) * NN);
        p0 = fmaf((float)a[0], u4[q], p0);
        p1 = fmaf((float)a[1], u4[q], p1);
      }
    }
    {
      float* Ca = Cbuf + (size_t)(it % 3) * CB + b * NN;
      atomAddF(Ca + 2 * t, p0);
      atomAddF(Ca + 2 * t + 1, p1);
    }
    // wave-level arrive: drain THIS wave's adds (+ zeroes), bump counter.
    asm volatile("s_waitcnt vmcnt(0)" ::: "memory");
    if (lane == 0)
      __hip_atomic_fetch_add(barB, 1u, __ATOMIC_RELAXED, __HIP_MEMORY_SCOPE_AGENT);
    // detect: 8 de-phased pollers, LDS-flag broadcast, then block sync.
    if (lane == 0) {
      unsigned target = (unsigned)ARRIVE_PER_IT * (unsigned)(it + 1);
      while (*dflag == 0) {
        unsigned v = __hip_atomic_load(barB, __ATOMIC_RELAXED,
                                       __HIP_MEMORY_SCOPE_AGENT);
        if (v >= target) { *dflag = 1; break; }
        __builtin_amdgcn_s_sleep(1);
      }
    }
    __syncthreads();
  }

  // final g (50th g-update) -> lv (log domain); slab 0 publishes Gf for bary
  {
    const float* Cg = Cbuf + (size_t)(49 % 3) * CB + b * NN;
    float2 cc = loadPart2(Cg + 2 * t);
    float g0 = BASE2 - LOG2F(cc.x);
    float g1 = BASE2 - LOG2F(cc.y);
    lv[PIDX(2 * t)] = g0;
    lv[PIDX(2 * t + 1)] = g1;
    if (slabId == 0) {
      Gf[b * NN + 2 * t] = g0;
      Gf[b * NN + 2 * t + 1] = g1;
    }
  }
  __syncthreads();
  ldsVec16p(lv, j0, gv);

  // fused marginals epilogue: re-read original a2 from global (L2/L3-hot).
#pragma unroll
  for (int r = 0; r < 8; ++r) {
    int rl = r0w + r;
    int i = slabId * 64 + rl;
    float fi = fv_l[rl];
    const _Float16* grow = A2 + ((size_t)b * NN + i) * NN;
    h8 qa = *(const h8*)(grow + j0);
    h8 qb = *(const h8*)(grow + 512 + j0);
    float fr = (float)i;
    float sr = 0.f, sl = 0.f;
#pragma unroll
    for (int k = 0; k < 8; ++k) {
      float a2a = (float)qa[k];
      float a2b = (float)qb[k];
      float Ta = EXP2F(a2a + fi + gv[k]);
      float Tb = EXP2F(a2b + fi + gv[8 + k]);
      sr += Ta + Tb;
      float ca = a2a + CPOS2 * fabsf(fr - (float)(j0 + k));
      float cb = a2b + CPOS2 * fabsf(fr - (float)(512 + j0 + k));
      sl = fmaf(Ta, ca, sl);
      sl = fmaf(Tb, cb, sl);
    }
    sr = waveReduceSum(sr);
    sl = waveReduceSum(sl);
    if (lane == 0) {
      rOut[b * NN + i] = sr;
      cOut[b * NN + i] = EXP2F(BASE2);
      Lrow[b * NN + i] = -C1 * sl;
    }
  }
}

// ---------------- K6: MFMA bary, LDS-staged ET ------------------------------
__global__ __launch_bounds__(256) void bary_mfma_kernel(
    const _Float16* __restrict__ A2, const _Float16* __restrict__ A2T,
    const float* __restrict__ F, const float* __restrict__ G,
    const float* __restrict__ r, const float* __restrict__ c,
    const _Float16* __restrict__ XT, const _Float16* __restrict__ YT,
    const float* __restrict__ X, const float* __restrict__ Y,
    float* __restrict__ baryA, float* __restrict__ baryB) {
  __shared__ float gl[NN];
  __shared__ float red[4];
  __shared__ _Float16 etile[2][256 * ETW];   // 2 x 20 KB
  int id = blockIdx.x + blockIdx.y * gridDim.x + blockIdx.z * gridDim.x * gridDim.y;
  int w = (id >> 3) + (id & 7) * 64;   // 0..511, contiguous per XCD
  const int I0 = (w & 15) * 64;
  const int bz = w >> 4;               // 0..31
  const int b = bz & 15;
  const int z = bz >> 4;
  const _Float16* P = z ? A2T : A2;
  const float* rowv = z ? G : F;
  const float* colv = z ? F : G;
  const float* denom = z ? c : r;
  const _Float16* EmbT = z ? XT : YT;
  const float* Ref = z ? Y : X;
  float* baryAcc = z ? baryB : baryA;
  const int t = threadIdx.x, lane = t & 63, wave = t >> 6;
  const int m = lane & 15, quad = lane >> 4;
  gl[t] = colv[b * NN + t];
  gl[t + 256] = colv[b * NN + t + 256];
  gl[t + 512] = colv[b * NN + t + 512];
  gl[t + 768] = colv[b * NN + t + 768];
  const int row = I0 + wave * 16 + m;
  const float fi = rowv[b * NN + row] + 10.0f;        // fold 2^10 scale
  const _Float16* Pr = P + (size_t)b * NN * NN + (size_t)row * NN + quad * 8;
  const _Float16* ET = EmbT + (size_t)b * DD * NN;

  auto stageET = [&](int buf, int kc) {
#pragma unroll
    for (int i = 0; i < 4; ++i) {
      int rr = (t >> 2) + i * 64;
      int ch = t & 3;
      h8 v = *(const h8*)(ET + (size_t)rr * NN + kc + ch * 8);
      *(h8*)(&etile[buf][rr * ETW + ch * 8]) = v;
    }
  };

  f32x4 acc[16];
#pragma unroll
  for (int i = 0; i < 16; ++i) acc[i] = (f32x4){0.f, 0.f, 0.f, 0.f};
  stageET(0, 0);
  h8 a2v = *(const h8*)(Pr);                          // prime A2 pipeline
  __syncthreads();                                    // covers gl + etile[0]
  int buf = 0;
  for (int kc = 0; kc < NN; kc += 32) {
    const int kn = kc + 32;
    if (kn < NN) stageET(buf ^ 1, kn);                // prefetch next tile
    h8 a2n = a2v;
    if (kn < NN) a2n = *(const h8*)(Pr + kn);         // prefetch next a2
    float4 g0 = *(const float4*)&gl[kc + quad * 8];
    float4 g1 = *(const float4*)&gl[kc + quad * 8 + 4];
    h8 af;
    af[0] = (_Float16)EXP2F((float)a2v[0] + fi + g0.x);
    af[1] = (_Float16)EXP2F((float)a2v[1] + fi + g0.y);
    af[2] = (_Float16)EXP2F((float)a2v[2] + fi + g0.z);
    af[3] = (_Float16)EXP2F((float)a2v[3] + fi + g0.w);
    af[4] = (_Float16)EXP2F((float)a2v[4] + fi + g1.x);
    af[5] = (_Float16)EXP2F((float)a2v[5] + fi + g1.y);
    af[6] = (_Float16)EXP2F((float)a2v[6] + fi + g1.z);
    af[7] = (_Float16)EXP2F((float)a2v[7] + fi + g1.w);
#pragma unroll
    for (int nt = 0; nt < 16; ++nt) {
      h8 bf = *(const h8*)(&etile[buf][(nt * 16 + m) * ETW + quad * 8]);
      acc[nt] = __builtin_amdgcn_mfma_f32_16x16x32_f16(af, bf, acc[nt], 0, 0, 0);
    }
    a2v = a2n;
    __syncthreads();                                  // etile[buf^1] ready
    buf ^= 1;
  }
  float vs = 0.f;
#pragma unroll
  for (int r4 = 0; r4 < 4; ++r4) {
    int iabs = I0 + wave * 16 + quad * 4 + r4;
    float inv = 1.0f / (1024.0f * (denom[b * NN + iabs] + 1e-8f));
    const float* Rrow = Ref + ((size_t)b * NN + iabs) * DD;
#pragma unroll
    for (int nt = 0; nt < 16; ++nt) {
      int d = nt * 16 + m;
      float val = Rrow[d] - acc[nt][r4] * inv;
      vs = fmaf(val, val, vs);
    }
  }
  vs = waveReduceSum(vs);
  if (lane == 0) red[wave] = vs;
  __syncthreads();
  if (t == 0) atomicAdd(baryAcc + b, red[0] + red[1] + red[2] + red[3]);
}

// ---------------- K7: partial global sums X*r, Y*c ----------------
__global__ __launch_bounds__(256) void xg_kernel(
    const float* __restrict__ X, const float* __restrict__ Y,
    const float* __restrict__ r, const float* __restrict__ c,
    float* __restrict__ xgp, float* __restrict__ ygp) {
  const int b = blockIdx.y, seg = blockIdx.x, d = threadIdx.x;
  float ax = 0.f, ay = 0.f;
  for (int ii = 0; ii < 256; ++ii) {
    int i = seg * 256 + ii;
    float rvv = r[b * NN + i];
    float cvv = c[b * NN + i];
    ax = fmaf(X[((size_t)b * NN + i) * DD + d], rvv, ax);
    ay = fmaf(Y[((size_t)b * NN + i) * DD + d], cvv, ay);
  }
  xgp[(size_t)(b * 4 + seg) * DD + d] = ax;
  ygp[(size_t)(b * 4 + seg) * DD + d] = ay;
}

// ---------------- K8: per-batch finalize ----------------
__global__ __launch_bounds__(256) void finalize_batch(
    const float* __restrict__ r, const float* __restrict__ c,
    const float* __restrict__ Lrow, const float* __restrict__ xgp,
    const float* __restrict__ ygp, const float* __restrict__ baryA,
    const float* __restrict__ baryB, float* __restrict__ lossArr) {
  const int b = blockIdx.x;
  const int t = threadIdx.x;
  __shared__ float sd[256];
  auto bsum = [&](float v) -> float {
    sd[t] = v; __syncthreads();
    for (int o = 128; o; o >>= 1) { if (t < o) sd[t] += sd[t + o]; __syncthreads(); }
    float res = sd[0]; __syncthreads();
    return res;
  };
  float vr = 0.f, vc = 0.f, vl = 0.f;
  for (int k = 0; k < 4; ++k) {
    int i = t + 256 * k;
    vr += r[b * NN + i];
    vc += c[b * NN + i];
    vl += Lrow[b * NN + i];
  }
  float sumR = bsum(vr);
  float sumC = bsum(vc);
  float Lmain = bsum(vl);
  float xg = (xgp[(size_t)(b * 4 + 0) * DD + t] + xgp[(size_t)(b * 4 + 1) * DD + t] +
              xgp[(size_t)(b * 4 + 2) * DD + t] + xgp[(size_t)(b * 4 + 3) * DD + t]) /
             (sumR + 1e-8f);
  float yg = (ygp[(size_t)(b * 4 + 0) * DD + t] + ygp[(size_t)(b * 4 + 1) * DD + t] +
              ygp[(size_t)(b * 4 + 2) * DD + t] + ygp[(size_t)(b * 4 + 3) * DD + t]) /
             (sumC + 1e-8f);
  float nx = bsum(xg * xg);
  float ny = bsum(yg * yg);
  float dt = bsum(xg * yg);
  if (t == 0) {
    float mx = fmaxf(sqrtf(nx), 1e-12f);
    float my = fmaxf(sqrtf(ny), 1e-12f);
    float cosv = dt / (mx * my);
    float lb = (baryA[b] + baryB[b]) * (1.0f / ((float)NN * (float)DD));
    lossArr[b] = Lmain + 0.5f * lb + 0.2f * (1.0f - cosv);
  }
}

__global__ void final_mean(const float* __restrict__ lossArr, float* __restrict__ out) {
  int t = threadIdx.x;
  float v = (t < BB) ? lossArr[t] : 0.f;
  v = waveReduceSum(v);
  if (t == 0) out[0] = v * (1.0f / BB);
}

// ---------------- launch ----------------
extern "C" void kernel_launch(void* const* d_in, const int* in_sizes, int n_in,
                              void* d_out, int out_size, void* d_ws, size_t ws_size,
                              hipStream_t stream) {
  const float* X = (const float*)d_in[0];
  const float* Y = (const float*)d_in[1];
  float* out = (float*)d_out;
  char* ws = (char*)d_ws;
  size_t off = 0;
  auto take = [&](size_t bytes) -> char* {
    char* p = ws + off;
    off = (off + bytes + 255) & ~(size_t)255;
    return p;
  };
  _Float16* Xh = (_Float16*)take((size_t)BB * NN * DD * 2);
  _Float16* Yh = (_Float16*)take((size_t)BB * NN * DD * 2);
  _Float16* XT_h = (_Float16*)take((size_t)BB * DD * NN * 2);
  _Float16* YT_h = (_Float16*)take((size_t)BB * DD * NN * 2);
  _Float16* A2 = (_Float16*)take((size_t)BB * NN * NN * 2);
  _Float16* A2T = (_Float16*)take((size_t)BB * NN * NN * 2);
  size_t zstart = off;
  float* Cbuf = (float*)take((size_t)3 * BB * NN * 4);   // triple-buffer col sums
  float* baryA = (float*)take(64);
  float* baryB = (float*)take(64);
  unsigned* bar = (unsigned*)take((size_t)BB * 16 * 4);  // per-batch barrier counters
  size_t zlen = off - zstart;
  float* Fv = (float*)take((size_t)BB * NN * 4);
  float* Gf = (float*)take((size_t)BB * NN * 4);
  float* r = (float*)take((size_t)BB * NN * 4);
  float* c = (float*)take((size_t)BB * NN * 4);
  float* Lrow = (float*)take((size_t)BB * NN * 4);
  float* xgp = (float*)take((size_t)BB * 4 * DD * 4);
  float* ygp = (float*)take((size_t)BB * 4 * DD * 4);
  float* lossArr = (float*)take(64);
  (void)in_sizes; (void)n_in; (void)out_size; (void)ws_size;

  (void)hipMemsetAsync(ws + zstart, 0, zlen, stream);

  normalize_kernel<<<dim3(2 * BB * NN / 4), dim3(256), 0, stream>>>(X, Y, Xh, Yh);
  transpose_kernel<<<dim3(NN / 64, DD / 64, 2 * BB), dim3(256), 0, stream>>>(X, Y, XT_h,
                                                                             YT_h);
  gemm_a2_kernel<<<dim3(NN / 128, NN / 128, BB), dim3(256), 0, stream>>>(Xh, Yh, A2,
                                                                         A2T);
  // persistent sinkhorn (50 iters + final g + marginals fused), PLAIN launch:
  // 256 blocks at 1 block/CU are trivially co-resident on 256 CUs.
  (void)hipFuncSetAttribute(reinterpret_cast<const void*>(sink_persist),
                            hipFuncAttributeMaxDynamicSharedMemorySize, SINK_SMEM);
  sink_persist<<<dim3(NSLAB, BB), dim3(512), SINK_SMEM, stream>>>(A2, Cbuf, Fv, Gf, r,
                                                                  c, Lrow, bar);
  bary_mfma_kernel<<<dim3(NN / 64, BB, 2), dim3(256), 0, stream>>>(
      A2, A2T, Fv, Gf, r, c, XT_h, YT_h, X, Y, baryA, baryB);
  xg_kernel<<<dim3(4, BB), dim3(256), 0, stream>>>(X, Y, r, c, xgp, ygp);
  finalize_batch<<<dim3(BB), dim3(256), 0, stream>>>(r, c, Lrow, xgp, ygp, baryA, baryB,
                                                     lossArr);
  final_mean<<<dim3(1), dim3(64), 0, stream>>>(lossArr, out);
}

// Round 14
// 494.772 us; speedup vs baseline: 1.5459x; 1.5459x over previous
//
#include <hip/hip_runtime.h>
#include <hip/hip_fp16.h>

#define BB 16
#define NN 1024
#define DD 256
#define NSLAB 16        // sinkhorn slabs per batch (64 rows each)
#define ETW 40          // bary: padded LDS row width (halves)

typedef _Float16 h8 __attribute__((ext_vector_type(8)));
typedef _Float16 hv4 __attribute__((ext_vector_type(4)));
typedef _Float16 h2 __attribute__((ext_vector_type(2)));
typedef float f32x4 __attribute__((ext_vector_type(4)));

#if __has_builtin(__builtin_amdgcn_exp2f)
#define EXP2F(x) __builtin_amdgcn_exp2f(x)
#else
#define EXP2F(x) exp2f(x)
#endif
#if __has_builtin(__builtin_amdgcn_logf)
#define LOG2F(x) __builtin_amdgcn_logf(x)
#else
#define LOG2F(x) log2f(x)
#endif

// log2-domain: A2s = -100*log2e*relu(1-S) - CPOS2*|i-j|   (pos prior folded in, fp16)
constexpr float K_A2  = -144.26950408889634f;                 // -100*log2(e)
constexpr float CPOS2 = (float)(0.2 * 1.4426950408889634 / 1023.0);
constexpr float C1    = 0.06931471805599453f;                 // ln2/10
constexpr float BASE2 = -10.0f;                               // log2(1/1024 + 1e-12)
constexpr float P2B   = 0x1p-10f;                             // 2^BASE2

#define PIDX(i) ((i) + ((i) >> 3))

__device__ __forceinline__ float waveReduceSum(float v) {
#pragma unroll
  for (int o = 32; o; o >>= 1) v += __shfl_xor(v, o);
  return v;
}

__device__ __forceinline__ void ldsVec16p(const float* lds, int j0, float (&out)[16]) {
#pragma unroll
  for (int k = 0; k < 8; ++k) {
    out[k] = lds[PIDX(j0 + k)];
    out[8 + k] = lds[PIDX(512 + j0 + k)];
  }
}

// ---------------- K1: normalize rows of X and Y -> fp16 ----------------
__global__ __launch_bounds__(256) void normalize_kernel(
    const float* __restrict__ X, const float* __restrict__ Y,
    _Float16* __restrict__ Xh, _Float16* __restrict__ Yh) {
  int wave = threadIdx.x >> 6;
  int lane = threadIdx.x & 63;
  int row = blockIdx.x * 4 + wave;
  const float* src;
  _Float16* dst;
  if (row < BB * NN) { src = X + (size_t)row * DD; dst = Xh + (size_t)row * DD; }
  else { int r2 = row - BB * NN; src = Y + (size_t)r2 * DD; dst = Yh + (size_t)r2 * DD; }
  float4 v = *(const float4*)(src + lane * 4);
  float ss = v.x * v.x + v.y * v.y + v.z * v.z + v.w * v.w;
  ss = waveReduceSum(ss);
  float sc = 1.0f / fmaxf(sqrtf(ss), 1e-12f);
  hv4 hv;
  hv[0] = (_Float16)(v.x * sc); hv[1] = (_Float16)(v.y * sc);
  hv[2] = (_Float16)(v.z * sc); hv[3] = (_Float16)(v.w * sc);
  *(hv4*)(dst + lane * 4) = hv;
}

// ---------------- K1b: tiled transpose X,Y -> fp16 [b][d][n] ----------------
__global__ __launch_bounds__(256) void transpose_kernel(
    const float* __restrict__ X, const float* __restrict__ Y,
    _Float16* __restrict__ XT, _Float16* __restrict__ YT) {
  __shared__ _Float16 tile[64][72];
  int zb = blockIdx.z;
  const float* E;
  _Float16* ET;
  if (zb < BB) { E = X + (size_t)zb * NN * DD; ET = XT + (size_t)zb * DD * NN; }
  else { E = Y + (size_t)(zb - BB) * NN * DD; ET = YT + (size_t)(zb - BB) * DD * NN; }
  int n0 = blockIdx.x * 64, d0 = blockIdx.y * 64;
  int t = threadIdx.x;
  int lr = t >> 2, lc = (t & 3) * 16;
#pragma unroll
  for (int k = 0; k < 16; k += 4) {
    float4 v = *(const float4*)(E + (size_t)(n0 + lr) * DD + d0 + lc + k);
    tile[lc + k + 0][lr] = (_Float16)v.x;
    tile[lc + k + 1][lr] = (_Float16)v.y;
    tile[lc + k + 2][lr] = (_Float16)v.z;
    tile[lc + k + 3][lr] = (_Float16)v.w;
  }
  __syncthreads();
#pragma unroll
  for (int k = 0; k < 16; k += 8) {
    h8 o;
#pragma unroll
    for (int j = 0; j < 8; ++j) o[j] = tile[lr][lc + k + j];
    *(h8*)(ET + (size_t)(d0 + lr) * NN + n0 + lc + k) = o;
  }
}

// ---------------- K2: ONE S-gemm per (b, tile), dual-write A2 + A2T ---------
__global__ __launch_bounds__(256) void gemm_a2_kernel(
    const _Float16* __restrict__ Xh, const _Float16* __restrict__ Yh,
    _Float16* __restrict__ A2, _Float16* __restrict__ A2T) {
  __shared__ _Float16 tile[128][136];
  const int b = blockIdx.z;
  const int I0 = blockIdx.y * 128;
  const int J0 = blockIdx.x * 128;
  const int lane = threadIdx.x & 63;
  const int wave = threadIdx.x >> 6;
  const int m = lane & 15, quad = lane >> 4;
  const _Float16* Abase = Xh + ((size_t)b * NN + I0 + wave * 32) * DD;
  const _Float16* Bbase = Yh + ((size_t)b * NN + J0) * DD;
  f32x4 acc[2][8] = {};
  for (int k0 = 0; k0 < DD; k0 += 32) {
    int koff = k0 + quad * 8;
    h8 a0 = *(const h8*)(Abase + (size_t)m * DD + koff);
    h8 a1 = *(const h8*)(Abase + (size_t)(m + 16) * DD + koff);
#pragma unroll
    for (int t = 0; t < 8; ++t) {
      h8 bf = *(const h8*)(Bbase + (size_t)(t * 16 + m) * DD + koff);
      acc[0][t] = __builtin_amdgcn_mfma_f32_16x16x32_f16(a0, bf, acc[0][t], 0, 0, 0);
      acc[1][t] = __builtin_amdgcn_mfma_f32_16x16x32_f16(a1, bf, acc[1][t], 0, 0, 0);
    }
  }
#pragma unroll
  for (int a = 0; a < 2; ++a)
#pragma unroll
    for (int t = 0; t < 8; ++t)
#pragma unroll
      for (int r = 0; r < 4; ++r) {
        int row = wave * 32 + a * 16 + quad * 4 + r;   // 0..127
        int col = t * 16 + m;                          // 0..127
        float s = acc[a][t][r];
        float ri = (float)(I0 + row);
        float ci = (float)(J0 + col);
        tile[row][col] =
            (_Float16)(K_A2 * fmaxf(1.0f - s, 0.0f) - CPOS2 * fabsf(ri - ci));
      }
  __syncthreads();
  const int t = threadIdx.x;
  // A2 write: row rr = t>>1, chunks (t&1)*8 + i (16 x 8 halves = 128 cols)
  {
    int rr = t >> 1;
    _Float16* Orow = A2 + ((size_t)b * NN + I0 + rr) * NN + J0;
#pragma unroll
    for (int i = 0; i < 8; ++i) {
      int cc = ((t & 1) * 8 + i) * 8;
      h8 o;
#pragma unroll
      for (int j = 0; j < 8; ++j) o[j] = tile[rr][cc + j];
      *(h8*)(Orow + cc) = o;
    }
  }
  // A2T write: A2T[J0+cr][I0+cc] = tile[cc][cr]
  {
    int ch = t & 15;                                  // cc chunk: cc = ch*8+j
    int crb = t >> 4;                                 // 0..15
#pragma unroll
    for (int i = 0; i < 8; ++i) {
      int cr = crb + i * 16;                          // 0..127
      h8 o;
#pragma unroll
      for (int j = 0; j < 8; ++j) o[j] = tile[ch * 8 + j][cr];
      *(h8*)(A2T + ((size_t)b * NN + J0 + cr) * NN + I0 + ch * 8) = o;
    }
  }
}

// ---------------- K3: persistent sinkhorn, LINEAR domain (R12 proven) -------
// 256 blocks = (16 slabs x 64 rows, 16 batches), 512 threads, 1 block/CU,
// PLAIN launch. Block-level barrier arrive (16/iter): R13's wave-level
// arrive (128/iter on ONE counter) regressed 325->572 us -- same-address
// agent atomics serialize ~60 ns each at L3. Keep fan-in low.
#define SINK_SMEM (131072 + 4608 + 256 + 256 + 256 + 256)

__device__ __forceinline__ void storePart2(float* p, float2 v) {
  union { float2 v; unsigned long long u; } cv;
  cv.v = v;
  __hip_atomic_store((unsigned long long*)p, cv.u, __ATOMIC_RELAXED,
                     __HIP_MEMORY_SCOPE_AGENT);
}

__device__ __forceinline__ float2 loadPart2(const float* p) {
  union { float2 v; unsigned long long u; } cv;
  cv.u = __hip_atomic_load((const unsigned long long*)p, __ATOMIC_RELAXED,
                           __HIP_MEMORY_SCOPE_AGENT);
  return cv.v;
}

__device__ __forceinline__ void atomAddF(float* p, float v) {
  (void)__hip_atomic_fetch_add(p, v, __ATOMIC_RELAXED, __HIP_MEMORY_SCOPE_AGENT);
}

// 16-B cache-bypassing (coherent) load: reads at the L3 coherence point,
// where the agent-scope atomic adds execute.
__device__ __forceinline__ float4 loadCoh4(const float* p) {
  float4 v;
  asm volatile("global_load_dwordx4 %0, %1, off sc0 sc1\n\ts_waitcnt vmcnt(0)"
               : "=v"(v)
               : "v"(p)
               : "memory");
  return v;
}

__global__ __launch_bounds__(512) void sink_persist(
    const _Float16* __restrict__ A2, float* __restrict__ Cbuf,
    float* __restrict__ Fv, float* __restrict__ Gf,
    float* __restrict__ rOut, float* __restrict__ cOut, float* __restrict__ Lrow,
    unsigned* __restrict__ bar) {
  extern __shared__ char smem[];
  _Float16* slab = (_Float16*)smem;                      // [64][1024] fp16 K'
  float* lv = (float*)(smem + 131072);                   // padded w, NN + NN/8
  float* f_l = (float*)(smem + 135680);                  // [64] u_i
  float* m_l = (float*)(smem + 135936);                  // [64] row max of a2
  float* fv_l = (float*)(smem + 136192);                 // [64] final log-f
  volatile unsigned* dflag = (volatile unsigned*)(smem + 136448);
  const int b = blockIdx.y;
  const int slabId = blockIdx.x;                         // 0..15
  const int t = threadIdx.x, lane = t & 63, wave = t >> 6;
  unsigned* barB = bar + b * 16;                         // 64 B padded counters

  // one-time: stage this block's 64-row A2 slab into LDS
  const _Float16* src = A2 + ((size_t)b * NN + slabId * 64) * NN;
  for (int e = t * 8; e < 64 * NN; e += 512 * 8)
    *(h8*)(slab + e) = *(const h8*)(src + e);
  __syncthreads();

  const int j0 = lane * 8;
  const int r0w = wave * 8;                              // 8 rows per wave

  // prologue: per-row max (batched shuffle reduce), then K' = exp2(a2 - m)
  {
    h8 qa8[8], qb8[8];
#pragma unroll
    for (int r = 0; r < 8; ++r) {
      qa8[r] = *(const h8*)(slab + (size_t)(r0w + r) * NN + j0);
      qb8[r] = *(const h8*)(slab + (size_t)(r0w + r) * NN + 512 + j0);
    }
    float mr[8];
#pragma unroll
    for (int r = 0; r < 8; ++r) {
      float m = (float)qa8[r][0];
#pragma unroll
      for (int k = 1; k < 8; ++k) m = fmaxf(m, (float)qa8[r][k]);
#pragma unroll
      for (int k = 0; k < 8; ++k) m = fmaxf(m, (float)qb8[r][k]);
      mr[r] = m;
    }
#pragma unroll
    for (int o = 32; o; o >>= 1)
#pragma unroll
      for (int r = 0; r < 8; ++r) mr[r] = fmaxf(mr[r], __shfl_xor(mr[r], o));
#pragma unroll
    for (int r = 0; r < 8; ++r) {
      h8 oa, ob;
#pragma unroll
      for (int k = 0; k < 8; ++k) {
        oa[k] = (_Float16)EXP2F((float)qa8[r][k] - mr[r]);
        ob[k] = (_Float16)EXP2F((float)qb8[r][k] - mr[r]);
      }
      *(h8*)(slab + (size_t)(r0w + r) * NN + j0) = oa;
      *(h8*)(slab + (size_t)(r0w + r) * NN + 512 + j0) = ob;
      if (lane == 0) m_l[r0w + r] = mr[r];
    }
  }

  const size_t CB = (size_t)BB * NN;
  float gv[16];

  for (int it = 0; it < 50; ++it) {
    // prologue: w from previous iteration's accumulated col sums
    if (it == 0) {
      lv[PIDX(2 * t)] = 1.0f;
      lv[PIDX(2 * t + 1)] = 1.0f;
    } else if (t < 256) {
      const float* Cr = Cbuf + (size_t)((it + 2) % 3) * CB + b * NN;  // (it-1)%3
      float4 cc = loadCoh4(Cr + 4 * t);
      lv[PIDX(4 * t + 0)] = P2B / cc.x;
      lv[PIDX(4 * t + 1)] = P2B / cc.y;
      lv[PIDX(4 * t + 2)] = P2B / cc.z;
      lv[PIDX(4 * t + 3)] = P2B / cc.w;
    }
    if (t == 0) *dflag = 0;
    __syncthreads();
    ldsVec16p(lv, j0, gv);
    // zero my stripe of the (it+1)%3 buffer (read at it+2; adds at it+1 --
    // all barrier-separated). Issued early to drain under pass A.
    {
      float* Cz = Cbuf + (size_t)((it + 1) % 3) * CB + b * NN;
      if (t < 32) storePart2(Cz + slabId * 64 + 2 * t, make_float2(0.f, 0.f));
    }
    // pass A: 8 rows per wave, s_i = sum K' * w (pure FMA, batched reduce)
    float sr8[8];
#pragma unroll
    for (int r = 0; r < 8; ++r) {
      h8 qa = *(const h8*)(slab + (size_t)(r0w + r) * NN + j0);
      h8 qb = *(const h8*)(slab + (size_t)(r0w + r) * NN + 512 + j0);
      float s = 0.f;
#pragma unroll
      for (int k = 0; k < 8; ++k) s = fmaf((float)qa[k], gv[k], s);
#pragma unroll
      for (int k = 0; k < 8; ++k) s = fmaf((float)qb[k], gv[8 + k], s);
      sr8[r] = s;
    }
#pragma unroll
    for (int o = 32; o; o >>= 1)
#pragma unroll
      for (int r = 0; r < 8; ++r) sr8[r] += __shfl_xor(sr8[r], o);
    if (lane == 0) {
#pragma unroll
      for (int r = 0; r < 8; ++r) {
        f_l[r0w + r] = P2B / sr8[r];                     // u_i
        if (it == 49) {
          float flog = BASE2 - m_l[r0w + r] - LOG2F(sr8[r]);
          fv_l[r0w + r] = flog;
          Fv[b * NN + slabId * 64 + r0w + r] = flog;
        }
      }
    }
    __syncthreads();
    // pass B: per-thread column pair over 64 LDS rows, then HW-accumulate
    float p0 = 0.f, p1 = 0.f;
    const _Float16* cp = slab + 2 * t;
#pragma unroll 4
    for (int i4 = 0; i4 < 16; ++i4) {
      float4 u4 = *(const float4*)&f_l[i4 * 4];
#pragma unroll
      for (int q = 0; q < 4; ++q) {
        h2 a = *(const h2*)(cp + (size_t)(i4 * 4 + q) * NN);
        p0 = fmaf((float)a[0], u4[q], p0);
        p1 = fmaf((float)a[1], u4[q], p1);
      }
    }
    {
      float* Ca = Cbuf + (size_t)(it % 3) * CB + b * NN;
      atomAddF(Ca + 2 * t, p0);
      atomAddF(Ca + 2 * t + 1, p1);
    }
    // per-batch 16-block barrier: __syncthreads drains vmcnt(0) (orders the
    // adds + zeroes before the counter bump). 8 de-phased pollers + LDS flag.
    __syncthreads();
    if (t == 0)
      __hip_atomic_fetch_add(barB, 1u, __ATOMIC_RELAXED, __HIP_MEMORY_SCOPE_AGENT);
    if (lane == 0) {
      unsigned target = (unsigned)NSLAB * (unsigned)(it + 1);
      while (*dflag == 0) {
        unsigned v = __hip_atomic_load(barB, __ATOMIC_RELAXED,
                                       __HIP_MEMORY_SCOPE_AGENT);
        if (v >= target) { *dflag = 1; break; }
        __builtin_amdgcn_s_sleep(1);
      }
    }
    __syncthreads();
  }

  // final g (50th g-update) -> lv (log domain); slab 0 publishes Gf for bary
  {
    const float* Cg = Cbuf + (size_t)(49 % 3) * CB + b * NN;
    float2 cc = loadPart2(Cg + 2 * t);
    float g0 = BASE2 - LOG2F(cc.x);
    float g1 = BASE2 - LOG2F(cc.y);
    lv[PIDX(2 * t)] = g0;
    lv[PIDX(2 * t + 1)] = g1;
    if (slabId == 0) {
      Gf[b * NN + 2 * t] = g0;
      Gf[b * NN + 2 * t + 1] = g1;
    }
  }
  __syncthreads();
  ldsVec16p(lv, j0, gv);

  // fused marginals epilogue: re-read original a2 from global (L2/L3-hot).
#pragma unroll
  for (int r = 0; r < 8; ++r) {
    int rl = r0w + r;
    int i = slabId * 64 + rl;
    float fi = fv_l[rl];
    const _Float16* grow = A2 + ((size_t)b * NN + i) * NN;
    h8 qa = *(const h8*)(grow + j0);
    h8 qb = *(const h8*)(grow + 512 + j0);
    float fr = (float)i;
    float sr = 0.f, sl = 0.f;
#pragma unroll
    for (int k = 0; k < 8; ++k) {
      float a2a = (float)qa[k];
      float a2b = (float)qb[k];
      float Ta = EXP2F(a2a + fi + gv[k]);
      float Tb = EXP2F(a2b + fi + gv[8 + k]);
      sr += Ta + Tb;
      float ca = a2a + CPOS2 * fabsf(fr - (float)(j0 + k));
      float cb = a2b + CPOS2 * fabsf(fr - (float)(512 + j0 + k));
      sl = fmaf(Ta, ca, sl);
      sl = fmaf(Tb, cb, sl);
    }
    sr = waveReduceSum(sr);
    sl = waveReduceSum(sl);
    if (lane == 0) {
      rOut[b * NN + i] = sr;
      cOut[b * NN + i] = EXP2F(BASE2);
      Lrow[b * NN + i] = -C1 * sl;
    }
  }
}

// ---------------- K6: MFMA bary, LDS-staged ET ------------------------------
__global__ __launch_bounds__(256) void bary_mfma_kernel(
    const _Float16* __restrict__ A2, const _Float16* __restrict__ A2T,
    const float* __restrict__ F, const float* __restrict__ G,
    const float* __restrict__ r, const float* __restrict__ c,
    const _Float16* __restrict__ XT, const _Float16* __restrict__ YT,
    const float* __restrict__ X, const float* __restrict__ Y,
    float* __restrict__ baryA, float* __restrict__ baryB) {
  __shared__ float gl[NN];
  __shared__ float red[4];
  __shared__ _Float16 etile[2][256 * ETW];   // 2 x 20 KB
  int id = blockIdx.x + blockIdx.y * gridDim.x + blockIdx.z * gridDim.x * gridDim.y;
  int w = (id >> 3) + (id & 7) * 64;   // 0..511, contiguous per XCD
  const int I0 = (w & 15) * 64;
  const int bz = w >> 4;               // 0..31
  const int b = bz & 15;
  const int z = bz >> 4;
  const _Float16* P = z ? A2T : A2;
  const float* rowv = z ? G : F;
  const float* colv = z ? F : G;
  const float* denom = z ? c : r;
  const _Float16* EmbT = z ? XT : YT;
  const float* Ref = z ? Y : X;
  float* baryAcc = z ? baryB : baryA;
  const int t = threadIdx.x, lane = t & 63, wave = t >> 6;
  const int m = lane & 15, quad = lane >> 4;
  gl[t] = colv[b * NN + t];
  gl[t + 256] = colv[b * NN + t + 256];
  gl[t + 512] = colv[b * NN + t + 512];
  gl[t + 768] = colv[b * NN + t + 768];
  const int row = I0 + wave * 16 + m;
  const float fi = rowv[b * NN + row] + 10.0f;        // fold 2^10 scale
  const _Float16* Pr = P + (size_t)b * NN * NN + (size_t)row * NN + quad * 8;
  const _Float16* ET = EmbT + (size_t)b * DD * NN;

  auto stageET = [&](int buf, int kc) {
#pragma unroll
    for (int i = 0; i < 4; ++i) {
      int rr = (t >> 2) + i * 64;
      int ch = t & 3;
      h8 v = *(const h8*)(ET + (size_t)rr * NN + kc + ch * 8);
      *(h8*)(&etile[buf][rr * ETW + ch * 8]) = v;
    }
  };

  f32x4 acc[16];
#pragma unroll
  for (int i = 0; i < 16; ++i) acc[i] = (f32x4){0.f, 0.f, 0.f, 0.f};
  stageET(0, 0);
  h8 a2v = *(const h8*)(Pr);                          // prime A2 pipeline
  __syncthreads();                                    // covers gl + etile[0]
  int buf = 0;
  for (int kc = 0; kc < NN; kc += 32) {
    const int kn = kc + 32;
    if (kn < NN) stageET(buf ^ 1, kn);                // prefetch next tile
    h8 a2n = a2v;
    if (kn < NN) a2n = *(const h8*)(Pr + kn);         // prefetch next a2
    float4 g0 = *(const float4*)&gl[kc + quad * 8];
    float4 g1 = *(const float4*)&gl[kc + quad * 8 + 4];
    h8 af;
    af[0] = (_Float16)EXP2F((float)a2v[0] + fi + g0.x);
    af[1] = (_Float16)EXP2F((float)a2v[1] + fi + g0.y);
    af[2] = (_Float16)EXP2F((float)a2v[2] + fi + g0.z);
    af[3] = (_Float16)EXP2F((float)a2v[3] + fi + g0.w);
    af[4] = (_Float16)EXP2F((float)a2v[4] + fi + g1.x);
    af[5] = (_Float16)EXP2F((float)a2v[5] + fi + g1.y);
    af[6] = (_Float16)EXP2F((float)a2v[6] + fi + g1.z);
    af[7] = (_Float16)EXP2F((float)a2v[7] + fi + g1.w);
#pragma unroll
    for (int nt = 0; nt < 16; ++nt) {
      h8 bf = *(const h8*)(&etile[buf][(nt * 16 + m) * ETW + quad * 8]);
      acc[nt] = __builtin_amdgcn_mfma_f32_16x16x32_f16(af, bf, acc[nt], 0, 0, 0);
    }
    a2v = a2n;
    __syncthreads();                                  // etile[buf^1] ready
    buf ^= 1;
  }
  float vs = 0.f;
#pragma unroll
  for (int r4 = 0; r4 < 4; ++r4) {
    int iabs = I0 + wave * 16 + quad * 4 + r4;
    float inv = 1.0f / (1024.0f * (denom[b * NN + iabs] + 1e-8f));
    const float* Rrow = Ref + ((size_t)b * NN + iabs) * DD;
#pragma unroll
    for (int nt = 0; nt < 16; ++nt) {
      int d = nt * 16 + m;
      float val = Rrow[d] - acc[nt][r4] * inv;
      vs = fmaf(val, val, vs);
    }
  }
  vs = waveReduceSum(vs);
  if (lane == 0) red[wave] = vs;
  __syncthreads();
  if (t == 0) atomicAdd(baryAcc + b, red[0] + red[1] + red[2] + red[3]);
}

// ---------------- K7: partial global sums X*r, Y*c ----------------
__global__ __launch_bounds__(256) void xg_kernel(
    const float* __restrict__ X, const float* __restrict__ Y,
    const float* __restrict__ r, const float* __restrict__ c,
    float* __restrict__ xgp, float* __restrict__ ygp) {
  const int b = blockIdx.y, seg = blockIdx.x, d = threadIdx.x;
  float ax = 0.f, ay = 0.f;
  for (int ii = 0; ii < 256; ++ii) {
    int i = seg * 256 + ii;
    float rvv = r[b * NN + i];
    float cvv = c[b * NN + i];
    ax = fmaf(X[((size_t)b * NN + i) * DD + d], rvv, ax);
    ay = fmaf(Y[((size_t)b * NN + i) * DD + d], cvv, ay);
  }
  xgp[(size_t)(b * 4 + seg) * DD + d] = ax;
  ygp[(size_t)(b * 4 + seg) * DD + d] = ay;
}

// ---------------- K8: per-batch finalize ----------------
__global__ __launch_bounds__(256) void finalize_batch(
    const float* __restrict__ r, const float* __restrict__ c,
    const float* __restrict__ Lrow, const float* __restrict__ xgp,
    const float* __restrict__ ygp, const float* __restrict__ baryA,
    const float* __restrict__ baryB, float* __restrict__ lossArr) {
  const int b = blockIdx.x;
  const int t = threadIdx.x;
  __shared__ float sd[256];
  auto bsum = [&](float v) -> float {
    sd[t] = v; __syncthreads();
    for (int o = 128; o; o >>= 1) { if (t < o) sd[t] += sd[t + o]; __syncthreads(); }
    float res = sd[0]; __syncthreads();
    return res;
  };
  float vr = 0.f, vc = 0.f, vl = 0.f;
  for (int k = 0; k < 4; ++k) {
    int i = t + 256 * k;
    vr += r[b * NN + i];
    vc += c[b * NN + i];
    vl += Lrow[b * NN + i];
  }
  float sumR = bsum(vr);
  float sumC = bsum(vc);
  float Lmain = bsum(vl);
  float xg = (xgp[(size_t)(b * 4 + 0) * DD + t] + xgp[(size_t)(b * 4 + 1) * DD + t] +
              xgp[(size_t)(b * 4 + 2) * DD + t] + xgp[(size_t)(b * 4 + 3) * DD + t]) /
             (sumR + 1e-8f);
  float yg = (ygp[(size_t)(b * 4 + 0) * DD + t] + ygp[(size_t)(b * 4 + 1) * DD + t] +
              ygp[(size_t)(b * 4 + 2) * DD + t] + ygp[(size_t)(b * 4 + 3) * DD + t]) /
             (sumC + 1e-8f);
  float nx = bsum(xg * xg);
  float ny = bsum(yg * yg);
  float dt = bsum(xg * yg);
  if (t == 0) {
    float mx = fmaxf(sqrtf(nx), 1e-12f);
    float my = fmaxf(sqrtf(ny), 1e-12f);
    float cosv = dt / (mx * my);
    float lb = (baryA[b] + baryB[b]) * (1.0f / ((float)NN * (float)DD));
    lossArr[b] = Lmain + 0.5f * lb + 0.2f * (1.0f - cosv);
  }
}

__global__ void final_mean(const float* __restrict__ lossArr, float* __restrict__ out) {
  int t = threadIdx.x;
  float v = (t < BB) ? lossArr[t] : 0.f;
  v = waveReduceSum(v);
  if (t == 0) out[0] = v * (1.0f / BB);
}

// ---------------- launch ----------------
extern "C" void kernel_launch(void* const* d_in, const int* in_sizes, int n_in,
                              void* d_out, int out_size, void* d_ws, size_t ws_size,
                              hipStream_t stream) {
  const float* X = (const float*)d_in[0];
  const float* Y = (const float*)d_in[1];
  float* out = (float*)d_out;
  char* ws = (char*)d_ws;
  size_t off = 0;
  auto take = [&](size_t bytes) -> char* {
    char* p = ws + off;
    off = (off + bytes + 255) & ~(size_t)255;
    return p;
  };
  _Float16* Xh = (_Float16*)take((size_t)BB * NN * DD * 2);
  _Float16* Yh = (_Float16*)take((size_t)BB * NN * DD * 2);
  _Float16* XT_h = (_Float16*)take((size_t)BB * DD * NN * 2);
  _Float16* YT_h = (_Float16*)take((size_t)BB * DD * NN * 2);
  _Float16* A2 = (_Float16*)take((size_t)BB * NN * NN * 2);
  _Float16* A2T = (_Float16*)take((size_t)BB * NN * NN * 2);
  size_t zstart = off;
  float* Cbuf = (float*)take((size_t)3 * BB * NN * 4);   // triple-buffer col sums
  float* baryA = (float*)take(64);
  float* baryB = (float*)take(64);
  unsigned* bar = (unsigned*)take((size_t)BB * 16 * 4);  // per-batch barrier counters
  size_t zlen = off - zstart;
  float* Fv = (float*)take((size_t)BB * NN * 4);
  float* Gf = (float*)take((size_t)BB * NN * 4);
  float* r = (float*)take((size_t)BB * NN * 4);
  float* c = (float*)take((size_t)BB * NN * 4);
  float* Lrow = (float*)take((size_t)BB * NN * 4);
  float* xgp = (float*)take((size_t)BB * 4 * DD * 4);
  float* ygp = (float*)take((size_t)BB * 4 * DD * 4);
  float* lossArr = (float*)take(64);
  (void)in_sizes; (void)n_in; (void)out_size; (void)ws_size;

  (void)hipMemsetAsync(ws + zstart, 0, zlen, stream);

  normalize_kernel<<<dim3(2 * BB * NN / 4), dim3(256), 0, stream>>>(X, Y, Xh, Yh);
  transpose_kernel<<<dim3(NN / 64, DD / 64, 2 * BB), dim3(256), 0, stream>>>(X, Y, XT_h,
                                                                             YT_h);
  gemm_a2_kernel<<<dim3(NN / 128, NN / 128, BB), dim3(256), 0, stream>>>(Xh, Yh, A2,
                                                                         A2T);
  // persistent sinkhorn (50 iters + final g + marginals fused), PLAIN launch:
  // 256 blocks at 1 block/CU are trivially co-resident on 256 CUs.
  (void)hipFuncSetAttribute(reinterpret_cast<const void*>(sink_persist),
                            hipFuncAttributeMaxDynamicSharedMemorySize, SINK_SMEM);
  sink_persist<<<dim3(NSLAB, BB), dim3(512), SINK_SMEM, stream>>>(A2, Cbuf, Fv, Gf, r,
                                                                  c, Lrow, bar);
  bary_mfma_kernel<<<dim3(NN / 64, BB, 2), dim3(256), 0, stream>>>(
      A2, A2T, Fv, Gf, r, c, XT_h, YT_h, X, Y, baryA, baryB);
  xg_kernel<<<dim3(4, BB), dim3(256), 0, stream>>>(X, Y, r, c, xgp, ygp);
  finalize_batch<<<dim3(BB), dim3(256), 0, stream>>>(r, c, Lrow, xgp, ygp, baryA, baryB,
                                                     lossArr);
  final_mean<<<dim3(1), dim3(64), 0, stream>>>(lossArr, out);
}

// Round 15
// 484.850 us; speedup vs baseline: 1.5775x; 1.0205x over previous
//
#include <hip/hip_runtime.h>
#include <hip/hip_fp16.h>

#define BB 16
#define NN 1024
#define DD 256
#define NSLAB 16        // sinkhorn slabs per batch (64 rows each)
#define ETW 40          // bary: padded LDS row width (halves)

typedef _Float16 h8 __attribute__((ext_vector_type(8)));
typedef _Float16 hv4 __attribute__((ext_vector_type(4)));
typedef _Float16 h2 __attribute__((ext_vector_type(2)));
typedef float f32x4 __attribute__((ext_vector_type(4)));

#if __has_builtin(__builtin_amdgcn_exp2f)
#define EXP2F(x) __builtin_amdgcn_exp2f(x)
#else
#define EXP2F(x) exp2f(x)
#endif
#if __has_builtin(__builtin_amdgcn_logf)
#define LOG2F(x) __builtin_amdgcn_logf(x)
#else
#define LOG2F(x) log2f(x)
#endif

// log2-domain: A2s = -100*log2e*relu(1-S) - CPOS2*|i-j|   (pos prior folded in, fp16)
constexpr float K_A2  = -144.26950408889634f;                 // -100*log2(e)
constexpr float CPOS2 = (float)(0.2 * 1.4426950408889634 / 1023.0);
constexpr float C1    = 0.06931471805599453f;                 // ln2/10
constexpr float BASE2 = -10.0f;                               // log2(1/1024 + 1e-12)
constexpr float P2B   = 0x1p-10f;                             // 2^BASE2

#define PIDX(i) ((i) + ((i) >> 3))

__device__ __forceinline__ float waveReduceSum(float v) {
#pragma unroll
  for (int o = 32; o; o >>= 1) v += __shfl_xor(v, o);
  return v;
}

__device__ __forceinline__ void ldsVec16p(const float* lds, int j0, float (&out)[16]) {
#pragma unroll
  for (int k = 0; k < 8; ++k) {
    out[k] = lds[PIDX(j0 + k)];
    out[8 + k] = lds[PIDX(512 + j0 + k)];
  }
}

// ---------------- K1: normalize rows of X and Y -> fp16 ----------------
__global__ __launch_bounds__(256) void normalize_kernel(
    const float* __restrict__ X, const float* __restrict__ Y,
    _Float16* __restrict__ Xh, _Float16* __restrict__ Yh) {
  int wave = threadIdx.x >> 6;
  int lane = threadIdx.x & 63;
  int row = blockIdx.x * 4 + wave;
  const float* src;
  _Float16* dst;
  if (row < BB * NN) { src = X + (size_t)row * DD; dst = Xh + (size_t)row * DD; }
  else { int r2 = row - BB * NN; src = Y + (size_t)r2 * DD; dst = Yh + (size_t)r2 * DD; }
  float4 v = *(const float4*)(src + lane * 4);
  float ss = v.x * v.x + v.y * v.y + v.z * v.z + v.w * v.w;
  ss = waveReduceSum(ss);
  float sc = 1.0f / fmaxf(sqrtf(ss), 1e-12f);
  hv4 hv;
  hv[0] = (_Float16)(v.x * sc); hv[1] = (_Float16)(v.y * sc);
  hv[2] = (_Float16)(v.z * sc); hv[3] = (_Float16)(v.w * sc);
  *(hv4*)(dst + lane * 4) = hv;
}

// ---------------- K1b: tiled transpose X,Y -> fp16 [b][d][n] ----------------
__global__ __launch_bounds__(256) void transpose_kernel(
    const float* __restrict__ X, const float* __restrict__ Y,
    _Float16* __restrict__ XT, _Float16* __restrict__ YT) {
  __shared__ _Float16 tile[64][72];
  int zb = blockIdx.z;
  const float* E;
  _Float16* ET;
  if (zb < BB) { E = X + (size_t)zb * NN * DD; ET = XT + (size_t)zb * DD * NN; }
  else { E = Y + (size_t)(zb - BB) * NN * DD; ET = YT + (size_t)(zb - BB) * DD * NN; }
  int n0 = blockIdx.x * 64, d0 = blockIdx.y * 64;
  int t = threadIdx.x;
  int lr = t >> 2, lc = (t & 3) * 16;
#pragma unroll
  for (int k = 0; k < 16; k += 4) {
    float4 v = *(const float4*)(E + (size_t)(n0 + lr) * DD + d0 + lc + k);
    tile[lc + k + 0][lr] = (_Float16)v.x;
    tile[lc + k + 1][lr] = (_Float16)v.y;
    tile[lc + k + 2][lr] = (_Float16)v.z;
    tile[lc + k + 3][lr] = (_Float16)v.w;
  }
  __syncthreads();
#pragma unroll
  for (int k = 0; k < 16; k += 8) {
    h8 o;
#pragma unroll
    for (int j = 0; j < 8; ++j) o[j] = tile[lr][lc + k + j];
    *(h8*)(ET + (size_t)(d0 + lr) * NN + n0 + lc + k) = o;
  }
}

// ---------------- K2: ONE S-gemm per (b, tile), dual-write A2 + A2T ---------
__global__ __launch_bounds__(256) void gemm_a2_kernel(
    const _Float16* __restrict__ Xh, const _Float16* __restrict__ Yh,
    _Float16* __restrict__ A2, _Float16* __restrict__ A2T) {
  __shared__ _Float16 tile[128][136];
  const int b = blockIdx.z;
  const int I0 = blockIdx.y * 128;
  const int J0 = blockIdx.x * 128;
  const int lane = threadIdx.x & 63;
  const int wave = threadIdx.x >> 6;
  const int m = lane & 15, quad = lane >> 4;
  const _Float16* Abase = Xh + ((size_t)b * NN + I0 + wave * 32) * DD;
  const _Float16* Bbase = Yh + ((size_t)b * NN + J0) * DD;
  f32x4 acc[2][8] = {};
  for (int k0 = 0; k0 < DD; k0 += 32) {
    int koff = k0 + quad * 8;
    h8 a0 = *(const h8*)(Abase + (size_t)m * DD + koff);
    h8 a1 = *(const h8*)(Abase + (size_t)(m + 16) * DD + koff);
#pragma unroll
    for (int t = 0; t < 8; ++t) {
      h8 bf = *(const h8*)(Bbase + (size_t)(t * 16 + m) * DD + koff);
      acc[0][t] = __builtin_amdgcn_mfma_f32_16x16x32_f16(a0, bf, acc[0][t], 0, 0, 0);
      acc[1][t] = __builtin_amdgcn_mfma_f32_16x16x32_f16(a1, bf, acc[1][t], 0, 0, 0);
    }
  }
#pragma unroll
  for (int a = 0; a < 2; ++a)
#pragma unroll
    for (int t = 0; t < 8; ++t)
#pragma unroll
      for (int r = 0; r < 4; ++r) {
        int row = wave * 32 + a * 16 + quad * 4 + r;   // 0..127
        int col = t * 16 + m;                          // 0..127
        float s = acc[a][t][r];
        float ri = (float)(I0 + row);
        float ci = (float)(J0 + col);
        tile[row][col] =
            (_Float16)(K_A2 * fmaxf(1.0f - s, 0.0f) - CPOS2 * fabsf(ri - ci));
      }
  __syncthreads();
  const int t = threadIdx.x;
  // A2 write: row rr = t>>1, chunks (t&1)*8 + i (16 x 8 halves = 128 cols)
  {
    int rr = t >> 1;
    _Float16* Orow = A2 + ((size_t)b * NN + I0 + rr) * NN + J0;
#pragma unroll
    for (int i = 0; i < 8; ++i) {
      int cc = ((t & 1) * 8 + i) * 8;
      h8 o;
#pragma unroll
      for (int j = 0; j < 8; ++j) o[j] = tile[rr][cc + j];
      *(h8*)(Orow + cc) = o;
    }
  }
  // A2T write: A2T[J0+cr][I0+cc] = tile[cc][cr]
  {
    int ch = t & 15;                                  // cc chunk: cc = ch*8+j
    int crb = t >> 4;                                 // 0..15
#pragma unroll
    for (int i = 0; i < 8; ++i) {
      int cr = crb + i * 16;                          // 0..127
      h8 o;
#pragma unroll
      for (int j = 0; j < 8; ++j) o[j] = tile[ch * 8 + j][cr];
      *(h8*)(A2T + ((size_t)b * NN + J0 + cr) * NN + I0 + ch * 8) = o;
    }
  }
}

// ---------------- K3: persistent sinkhorn, LINEAR domain (R12 proven) -------
// 256 blocks = (16 slabs x 64 rows, 16 batches), 512 threads, 1 block/CU,
// PLAIN launch. Block-level barrier arrive (16/iter): R13's wave-level
// arrive (128/iter on ONE counter) regressed 325->572 us -- same-address
// agent atomics serialize ~60 ns each at L3. Keep fan-in low.
#define SINK_SMEM (131072 + 4608 + 256 + 256 + 256 + 256)

__device__ __forceinline__ void storePart2(float* p, float2 v) {
  union { float2 v; unsigned long long u; } cv;
  cv.v = v;
  __hip_atomic_store((unsigned long long*)p, cv.u, __ATOMIC_RELAXED,
                     __HIP_MEMORY_SCOPE_AGENT);
}

__device__ __forceinline__ float2 loadPart2(const float* p) {
  union { float2 v; unsigned long long u; } cv;
  cv.u = __hip_atomic_load((const unsigned long long*)p, __ATOMIC_RELAXED,
                           __HIP_MEMORY_SCOPE_AGENT);
  return cv.v;
}

__device__ __forceinline__ void atomAddF(float* p, float v) {
  (void)__hip_atomic_fetch_add(p, v, __ATOMIC_RELAXED, __HIP_MEMORY_SCOPE_AGENT);
}

// 16-B cache-bypassing (coherent) load: reads at the L3 coherence point,
// where the agent-scope atomic adds execute.
__device__ __forceinline__ float4 loadCoh4(const float* p) {
  float4 v;
  asm volatile("global_load_dwordx4 %0, %1, off sc0 sc1\n\ts_waitcnt vmcnt(0)"
               : "=v"(v)
               : "v"(p)
               : "memory");
  return v;
}

__global__ __launch_bounds__(512) void sink_persist(
    const _Float16* __restrict__ A2, float* __restrict__ Cbuf,
    float* __restrict__ Fv, float* __restrict__ Gf,
    float* __restrict__ rOut, float* __restrict__ cOut, float* __restrict__ Lrow,
    unsigned* __restrict__ bar) {
  extern __shared__ char smem[];
  _Float16* slab = (_Float16*)smem;                      // [64][1024] fp16 K'
  float* lv = (float*)(smem + 131072);                   // padded w, NN + NN/8
  float* f_l = (float*)(smem + 135680);                  // [64] u_i
  float* m_l = (float*)(smem + 135936);                  // [64] row max of a2
  float* fv_l = (float*)(smem + 136192);                 // [64] final log-f
  volatile unsigned* dflag = (volatile unsigned*)(smem + 136448);
  const int b = blockIdx.y;
  const int slabId = blockIdx.x;                         // 0..15
  const int t = threadIdx.x, lane = t & 63, wave = t >> 6;
  unsigned* barB = bar + b * 16;                         // 64 B padded counters

  // one-time: stage this block's 64-row A2 slab into LDS
  const _Float16* src = A2 + ((size_t)b * NN + slabId * 64) * NN;
  for (int e = t * 8; e < 64 * NN; e += 512 * 8)
    *(h8*)(slab + e) = *(const h8*)(src + e);
  __syncthreads();

  const int j0 = lane * 8;
  const int r0w = wave * 8;                              // 8 rows per wave

  // prologue: per-row max (batched shuffle reduce), then K' = exp2(a2 - m)
  {
    h8 qa8[8], qb8[8];
#pragma unroll
    for (int r = 0; r < 8; ++r) {
      qa8[r] = *(const h8*)(slab + (size_t)(r0w + r) * NN + j0);
      qb8[r] = *(const h8*)(slab + (size_t)(r0w + r) * NN + 512 + j0);
    }
    float mr[8];
#pragma unroll
    for (int r = 0; r < 8; ++r) {
      float m = (float)qa8[r][0];
#pragma unroll
      for (int k = 1; k < 8; ++k) m = fmaxf(m, (float)qa8[r][k]);
#pragma unroll
      for (int k = 0; k < 8; ++k) m = fmaxf(m, (float)qb8[r][k]);
      mr[r] = m;
    }
#pragma unroll
    for (int o = 32; o; o >>= 1)
#pragma unroll
      for (int r = 0; r < 8; ++r) mr[r] = fmaxf(mr[r], __shfl_xor(mr[r], o));
#pragma unroll
    for (int r = 0; r < 8; ++r) {
      h8 oa, ob;
#pragma unroll
      for (int k = 0; k < 8; ++k) {
        oa[k] = (_Float16)EXP2F((float)qa8[r][k] - mr[r]);
        ob[k] = (_Float16)EXP2F((float)qb8[r][k] - mr[r]);
      }
      *(h8*)(slab + (size_t)(r0w + r) * NN + j0) = oa;
      *(h8*)(slab + (size_t)(r0w + r) * NN + 512 + j0) = ob;
      if (lane == 0) m_l[r0w + r] = mr[r];
    }
  }

  const size_t CB = (size_t)BB * NN;
  float gv[16];

  for (int it = 0; it < 50; ++it) {
    // prologue: w from previous iteration's accumulated col sums
    if (it == 0) {
      lv[PIDX(2 * t)] = 1.0f;
      lv[PIDX(2 * t + 1)] = 1.0f;
    } else if (t < 256) {
      const float* Cr = Cbuf + (size_t)((it + 2) % 3) * CB + b * NN;  // (it-1)%3
      float4 cc = loadCoh4(Cr + 4 * t);
      lv[PIDX(4 * t + 0)] = P2B / cc.x;
      lv[PIDX(4 * t + 1)] = P2B / cc.y;
      lv[PIDX(4 * t + 2)] = P2B / cc.z;
      lv[PIDX(4 * t + 3)] = P2B / cc.w;
    }
    if (t == 0) *dflag = 0;
    __syncthreads();
    ldsVec16p(lv, j0, gv);
    // zero my stripe of the (it+1)%3 buffer (read at it+2; adds at it+1 --
    // all barrier-separated). Issued early to drain under pass A.
    {
      float* Cz = Cbuf + (size_t)((it + 1) % 3) * CB + b * NN;
      if (t < 32) storePart2(Cz + slabId * 64 + 2 * t, make_float2(0.f, 0.f));
    }
    // pass A: 8 rows per wave, s_i = sum K' * w (pure FMA, batched reduce)
    float sr8[8];
#pragma unroll
    for (int r = 0; r < 8; ++r) {
      h8 qa = *(const h8*)(slab + (size_t)(r0w + r) * NN + j0);
      h8 qb = *(const h8*)(slab + (size_t)(r0w + r) * NN + 512 + j0);
      float s = 0.f;
#pragma unroll
      for (int k = 0; k < 8; ++k) s = fmaf((float)qa[k], gv[k], s);
#pragma unroll
      for (int k = 0; k < 8; ++k) s = fmaf((float)qb[k], gv[8 + k], s);
      sr8[r] = s;
    }
#pragma unroll
    for (int o = 32; o; o >>= 1)
#pragma unroll
      for (int r = 0; r < 8; ++r) sr8[r] += __shfl_xor(sr8[r], o);
    if (lane == 0) {
#pragma unroll
      for (int r = 0; r < 8; ++r) {
        f_l[r0w + r] = P2B / sr8[r];                     // u_i
        if (it == 49) {
          float flog = BASE2 - m_l[r0w + r] - LOG2F(sr8[r]);
          fv_l[r0w + r] = flog;
          Fv[b * NN + slabId * 64 + r0w + r] = flog;
        }
      }
    }
    __syncthreads();
    // pass B: per-thread column pair over 64 LDS rows, then HW-accumulate
    float p0 = 0.f, p1 = 0.f;
    const _Float16* cp = slab + 2 * t;
#pragma unroll 4
    for (int i4 = 0; i4 < 16; ++i4) {
      float4 u4 = *(const float4*)&f_l[i4 * 4];
#pragma unroll
      for (int q = 0; q < 4; ++q) {
        h2 a = *(const h2*)(cp + (size_t)(i4 * 4 + q) * NN);
        p0 = fmaf((float)a[0], u4[q], p0);
        p1 = fmaf((float)a[1], u4[q], p1);
      }
    }
    {
      float* Ca = Cbuf + (size_t)(it % 3) * CB + b * NN;
      atomAddF(Ca + 2 * t, p0);
      atomAddF(Ca + 2 * t + 1, p1);
    }
    // per-batch 16-block barrier: __syncthreads drains vmcnt(0) (orders the
    // adds + zeroes before the counter bump). 8 de-phased pollers + LDS flag.
    __syncthreads();
    if (t == 0)
      __hip_atomic_fetch_add(barB, 1u, __ATOMIC_RELAXED, __HIP_MEMORY_SCOPE_AGENT);
    if (lane == 0) {
      unsigned target = (unsigned)NSLAB * (unsigned)(it + 1);
      while (*dflag == 0) {
        unsigned v = __hip_atomic_load(barB, __ATOMIC_RELAXED,
                                       __HIP_MEMORY_SCOPE_AGENT);
        if (v >= target) { *dflag = 1; break; }
        __builtin_amdgcn_s_sleep(1);
      }
    }
    __syncthreads();
  }

  // final g (50th g-update) -> lv (log domain); slab 0 publishes Gf for bary
  {
    const float* Cg = Cbuf + (size_t)(49 % 3) * CB + b * NN;
    float2 cc = loadPart2(Cg + 2 * t);
    float g0 = BASE2 - LOG2F(cc.x);
    float g1 = BASE2 - LOG2F(cc.y);
    lv[PIDX(2 * t)] = g0;
    lv[PIDX(2 * t + 1)] = g1;
    if (slabId == 0) {
      Gf[b * NN + 2 * t] = g0;
      Gf[b * NN + 2 * t + 1] = g1;
    }
  }
  __syncthreads();
  ldsVec16p(lv, j0, gv);

  // fused marginals epilogue: re-read original a2 from global (L2/L3-hot).
#pragma unroll
  for (int r = 0; r < 8; ++r) {
    int rl = r0w + r;
    int i = slabId * 64 + rl;
    float fi = fv_l[rl];
    const _Float16* grow = A2 + ((size_t)b * NN + i) * NN;
    h8 qa = *(const h8*)(grow + j0);
    h8 qb = *(const h8*)(grow + 512 + j0);
    float fr = (float)i;
    float sr = 0.f, sl = 0.f;
#pragma unroll
    for (int k = 0; k < 8; ++k) {
      float a2a = (float)qa[k];
      float a2b = (float)qb[k];
      float Ta = EXP2F(a2a + fi + gv[k]);
      float Tb = EXP2F(a2b + fi + gv[8 + k]);
      sr += Ta + Tb;
      float ca = a2a + CPOS2 * fabsf(fr - (float)(j0 + k));
      float cb = a2b + CPOS2 * fabsf(fr - (float)(512 + j0 + k));
      sl = fmaf(Ta, ca, sl);
      sl = fmaf(Tb, cb, sl);
    }
    sr = waveReduceSum(sr);
    sl = waveReduceSum(sl);
    if (lane == 0) {
      rOut[b * NN + i] = sr;
      cOut[b * NN + i] = EXP2F(BASE2);
      Lrow[b * NN + i] = -C1 * sl;
    }
  }
}

// ---------------- K6: MFMA bary, LDS-staged ET ------------------------------
__global__ __launch_bounds__(256) void bary_mfma_kernel(
    const _Float16* __restrict__ A2, const _Float16* __restrict__ A2T,
    const float* __restrict__ F, const float* __restrict__ G,
    const float* __restrict__ r, const float* __restrict__ c,
    const _Float16* __restrict__ XT, const _Float16* __restrict__ YT,
    const float* __restrict__ X, const float* __restrict__ Y,
    float* __restrict__ baryA, float* __restrict__ baryB) {
  __shared__ float gl[NN];
  __shared__ float red[4];
  __shared__ _Float16 etile[2][256 * ETW];   // 2 x 20 KB
  int id = blockIdx.x + blockIdx.y * gridDim.x + blockIdx.z * gridDim.x * gridDim.y;
  int w = (id >> 3) + (id & 7) * 64;   // 0..511, contiguous per XCD
  const int I0 = (w & 15) * 64;
  const int bz = w >> 4;               // 0..31
  const int b = bz & 15;
  const int z = bz >> 4;
  const _Float16* P = z ? A2T : A2;
  const float* rowv = z ? G : F;
  const float* colv = z ? F : G;
  const float* denom = z ? c : r;
  const _Float16* EmbT = z ? XT : YT;
  const float* Ref = z ? Y : X;
  float* baryAcc = z ? baryB : baryA;
  const int t = threadIdx.x, lane = t & 63, wave = t >> 6;
  const int m = lane & 15, quad = lane >> 4;
  gl[t] = colv[b * NN + t];
  gl[t + 256] = colv[b * NN + t + 256];
  gl[t + 512] = colv[b * NN + t + 512];
  gl[t + 768] = colv[b * NN + t + 768];
  const int row = I0 + wave * 16 + m;
  const float fi = rowv[b * NN + row] + 10.0f;        // fold 2^10 scale
  const _Float16* Pr = P + (size_t)b * NN * NN + (size_t)row * NN + quad * 8;
  const _Float16* ET = EmbT + (size_t)b * DD * NN;

  auto stageET = [&](int buf, int kc) {
#pragma unroll
    for (int i = 0; i < 4; ++i) {
      int rr = (t >> 2) + i * 64;
      int ch = t & 3;
      h8 v = *(const h8*)(ET + (size_t)rr * NN + kc + ch * 8);
      *(h8*)(&etile[buf][rr * ETW + ch * 8]) = v;
    }
  };

  f32x4 acc[16];
#pragma unroll
  for (int i = 0; i < 16; ++i) acc[i] = (f32x4){0.f, 0.f, 0.f, 0.f};
  stageET(0, 0);
  h8 a2v = *(const h8*)(Pr);                          // prime A2 pipeline
  __syncthreads();                                    // covers gl + etile[0]
  int buf = 0;
  for (int kc = 0; kc < NN; kc += 32) {
    const int kn = kc + 32;
    if (kn < NN) stageET(buf ^ 1, kn);                // prefetch next tile
    h8 a2n = a2v;
    if (kn < NN) a2n = *(const h8*)(Pr + kn);         // prefetch next a2
    float4 g0 = *(const float4*)&gl[kc + quad * 8];
    float4 g1 = *(const float4*)&gl[kc + quad * 8 + 4];
    h8 af;
    af[0] = (_Float16)EXP2F((float)a2v[0] + fi + g0.x);
    af[1] = (_Float16)EXP2F((float)a2v[1] + fi + g0.y);
    af[2] = (_Float16)EXP2F((float)a2v[2] + fi + g0.z);
    af[3] = (_Float16)EXP2F((float)a2v[3] + fi + g0.w);
    af[4] = (_Float16)EXP2F((float)a2v[4] + fi + g1.x);
    af[5] = (_Float16)EXP2F((float)a2v[5] + fi + g1.y);
    af[6] = (_Float16)EXP2F((float)a2v[6] + fi + g1.z);
    af[7] = (_Float16)EXP2F((float)a2v[7] + fi + g1.w);
#pragma unroll
    for (int nt = 0; nt < 16; ++nt) {
      h8 bf = *(const h8*)(&etile[buf][(nt * 16 + m) * ETW + quad * 8]);
      acc[nt] = __builtin_amdgcn_mfma_f32_16x16x32_f16(af, bf, acc[nt], 0, 0, 0);
    }
    a2v = a2n;
    __syncthreads();                                  // etile[buf^1] ready
    buf ^= 1;
  }
  float vs = 0.f;
#pragma unroll
  for (int r4 = 0; r4 < 4; ++r4) {
    int iabs = I0 + wave * 16 + quad * 4 + r4;
    float inv = 1.0f / (1024.0f * (denom[b * NN + iabs] + 1e-8f));
    const float* Rrow = Ref + ((size_t)b * NN + iabs) * DD;
#pragma unroll
    for (int nt = 0; nt < 16; ++nt) {
      int d = nt * 16 + m;
      float val = Rrow[d] - acc[nt][r4] * inv;
      vs = fmaf(val, val, vs);
    }
  }
  vs = waveReduceSum(vs);
  if (lane == 0) red[wave] = vs;
  __syncthreads();
  if (t == 0) atomicAdd(baryAcc + b, red[0] + red[1] + red[2] + red[3]);
}

// ---------------- K7: partial global sums X*r, Y*c (256 blocks) -------------
// 16 segs x 64 rows per batch: 4x the blocks of the old version -> full-device
// HBM issue rate for the 32 MB X/Y read (was 64 blocks = BW-starved ~20 us).
__global__ __launch_bounds__(256) void xg_kernel(
    const float* __restrict__ X, const float* __restrict__ Y,
    const float* __restrict__ r, const float* __restrict__ c,
    float* __restrict__ xgp, float* __restrict__ ygp) {
  const int b = blockIdx.y, seg = blockIdx.x, d = threadIdx.x;
  float ax = 0.f, ay = 0.f;
  for (int ii = 0; ii < 64; ++ii) {
    int i = seg * 64 + ii;
    float rvv = r[b * NN + i];
    float cvv = c[b * NN + i];
    ax = fmaf(X[((size_t)b * NN + i) * DD + d], rvv, ax);
    ay = fmaf(Y[((size_t)b * NN + i) * DD + d], cvv, ay);
  }
  xgp[(size_t)(b * 16 + seg) * DD + d] = ax;
  ygp[(size_t)(b * 16 + seg) * DD + d] = ay;
}

// ---------------- K8: per-batch finalize + fused final mean ----------------
// Last-arriving block (agent counter; lossArr store drained before bump)
// reproduces final_mean's exact shuffle tree -> bit-identical, one fewer
// dispatch.
__global__ __launch_bounds__(256) void finalize_batch(
    const float* __restrict__ r, const float* __restrict__ c,
    const float* __restrict__ Lrow, const float* __restrict__ xgp,
    const float* __restrict__ ygp, const float* __restrict__ baryA,
    const float* __restrict__ baryB, float* __restrict__ lossArr,
    unsigned* __restrict__ fctr, float* __restrict__ out) {
  const int b = blockIdx.x;
  const int t = threadIdx.x;
  __shared__ float sd[256];
  __shared__ unsigned doMean;
  auto bsum = [&](float v) -> float {
    sd[t] = v; __syncthreads();
    for (int o = 128; o; o >>= 1) { if (t < o) sd[t] += sd[t + o]; __syncthreads(); }
    float res = sd[0]; __syncthreads();
    return res;
  };
  float vr = 0.f, vc = 0.f, vl = 0.f;
  for (int k = 0; k < 4; ++k) {
    int i = t + 256 * k;
    vr += r[b * NN + i];
    vc += c[b * NN + i];
    vl += Lrow[b * NN + i];
  }
  float sumR = bsum(vr);
  float sumC = bsum(vc);
  float Lmain = bsum(vl);
  float xs = 0.f, ys = 0.f;
#pragma unroll
  for (int s = 0; s < 16; ++s) {
    xs += xgp[(size_t)(b * 16 + s) * DD + t];
    ys += ygp[(size_t)(b * 16 + s) * DD + t];
  }
  float xg = xs / (sumR + 1e-8f);
  float yg = ys / (sumC + 1e-8f);
  float nx = bsum(xg * xg);
  float ny = bsum(yg * yg);
  float dt = bsum(xg * yg);
  if (t == 0) {
    float mx = fmaxf(sqrtf(nx), 1e-12f);
    float my = fmaxf(sqrtf(ny), 1e-12f);
    float cosv = dt / (mx * my);
    float lb = (baryA[b] + baryB[b]) * (1.0f / ((float)NN * (float)DD));
    lossArr[b] = Lmain + 0.5f * lb + 0.2f * (1.0f - cosv);
    asm volatile("s_waitcnt vmcnt(0)" ::: "memory");    // drain before bump
    unsigned prev = __hip_atomic_fetch_add(fctr, 1u, __ATOMIC_RELAXED,
                                           __HIP_MEMORY_SCOPE_AGENT);
    doMean = (prev == (unsigned)BB - 1) ? 1u : 0u;
  }
  __syncthreads();
  if (doMean && t < 64) {
    float4 cc = make_float4(0.f, 0.f, 0.f, 0.f);
    if (t < 4) cc = loadCoh4(lossArr + 4 * t);          // coherent (other blocks)
    int srcl = t >> 2;
    float vx = __shfl(cc.x, srcl);
    float vy = __shfl(cc.y, srcl);
    float vz = __shfl(cc.z, srcl);
    float vw = __shfl(cc.w, srcl);
    int c4 = t & 3;
    float v = (c4 == 0) ? vx : (c4 == 1) ? vy : (c4 == 2) ? vz : vw;  // lossArr[t], t<16
    v = waveReduceSum(v);                               // same tree as final_mean
    if (t == 0) out[0] = v * (1.0f / BB);
  }
}

// ---------------- launch ----------------
extern "C" void kernel_launch(void* const* d_in, const int* in_sizes, int n_in,
                              void* d_out, int out_size, void* d_ws, size_t ws_size,
                              hipStream_t stream) {
  const float* X = (const float*)d_in[0];
  const float* Y = (const float*)d_in[1];
  float* out = (float*)d_out;
  char* ws = (char*)d_ws;
  size_t off = 0;
  auto take = [&](size_t bytes) -> char* {
    char* p = ws + off;
    off = (off + bytes + 255) & ~(size_t)255;
    return p;
  };
  _Float16* Xh = (_Float16*)take((size_t)BB * NN * DD * 2);
  _Float16* Yh = (_Float16*)take((size_t)BB * NN * DD * 2);
  _Float16* XT_h = (_Float16*)take((size_t)BB * DD * NN * 2);
  _Float16* YT_h = (_Float16*)take((size_t)BB * DD * NN * 2);
  _Float16* A2 = (_Float16*)take((size_t)BB * NN * NN * 2);
  _Float16* A2T = (_Float16*)take((size_t)BB * NN * NN * 2);
  size_t zstart = off;
  float* Cbuf = (float*)take((size_t)3 * BB * NN * 4);   // triple-buffer col sums
  float* baryA = (float*)take(64);
  float* baryB = (float*)take(64);
  unsigned* bar = (unsigned*)take((size_t)BB * 16 * 4);  // per-batch barrier counters
  unsigned* fctr = (unsigned*)take(64);                  // finalize arrival counter
  size_t zlen = off - zstart;
  float* Fv = (float*)take((size_t)BB * NN * 4);
  float* Gf = (float*)take((size_t)BB * NN * 4);
  float* r = (float*)take((size_t)BB * NN * 4);
  float* c = (float*)take((size_t)BB * NN * 4);
  float* Lrow = (float*)take((size_t)BB * NN * 4);
  float* xgp = (float*)take((size_t)BB * 16 * DD * 4);
  float* ygp = (float*)take((size_t)BB * 16 * DD * 4);
  float* lossArr = (float*)take(64);
  (void)in_sizes; (void)n_in; (void)out_size; (void)ws_size;

  (void)hipMemsetAsync(ws + zstart, 0, zlen, stream);

  normalize_kernel<<<dim3(2 * BB * NN / 4), dim3(256), 0, stream>>>(X, Y, Xh, Yh);
  transpose_kernel<<<dim3(NN / 64, DD / 64, 2 * BB), dim3(256), 0, stream>>>(X, Y, XT_h,
                                                                             YT_h);
  gemm_a2_kernel<<<dim3(NN / 128, NN / 128, BB), dim3(256), 0, stream>>>(Xh, Yh, A2,
                                                                         A2T);
  // persistent sinkhorn (50 iters + final g + marginals fused), PLAIN launch:
  // 256 blocks at 1 block/CU are trivially co-resident on 256 CUs.
  (void)hipFuncSetAttribute(reinterpret_cast<const void*>(sink_persist),
                            hipFuncAttributeMaxDynamicSharedMemorySize, SINK_SMEM);
  sink_persist<<<dim3(NSLAB, BB), dim3(512), SINK_SMEM, stream>>>(A2, Cbuf, Fv, Gf, r,
                                                                  c, Lrow, bar);
  bary_mfma_kernel<<<dim3(NN / 64, BB, 2), dim3(256), 0, stream>>>(
      A2, A2T, Fv, Gf, r, c, XT_h, YT_h, X, Y, baryA, baryB);
  xg_kernel<<<dim3(16, BB), dim3(256), 0, stream>>>(X, Y, r, c, xgp, ygp);
  finalize_batch<<<dim3(BB), dim3(256), 0, stream>>>(r, c, Lrow, xgp, ygp, baryA, baryB,
                                                     lossArr, fctr, out);
}